// Round 15
// baseline (86.860 us; speedup 1.0000x reference)
//
#include <hip/hip_runtime.h>

typedef unsigned long long u64;

constexpr int D = 48, H = 384, W = 384;
constexpr int WPR = 6;                    // 384 bits / 64 per row (real words)
constexpr int PADW = 8;                   // padded words per row: [pad, w0..w5, pad]
constexpr int NVOX = D * H * W;           // 7,077,888
constexpr int NWVOL = D * H * WPR;        // 110,592 packed words per volume
constexpr int MPAD2 = 52;                 // padded change-mask array (u64s)
constexpr int NXY = (D + 2) * PADW;       // padded words per xy slice = 400
constexpr int NTILE = D * 36;             // 1728 bit-transpose tiles (64x64)

// Banded z phase-A: dependency radius grows 1 row/subpass, so after KA
// subpasses the BAND-row core (with HALO>=KA halo rows) is exact.
constexpr int BAND = 96;
constexpr int HALO = 16;
constexpr int KA = 16;                    // even -> parity preserved for phase-B
constexpr int BROWS = BAND + 2 * HALO;    // 128 loaded rows
constexpr int NBAND = H / BAND;           // 4

// full adder: s = a+b+c (bit-sliced), cy = carry
__device__ __forceinline__ void fa(u64 a, u64 b, u64 c, u64& s, u64& cy) {
  u64 x = a ^ b;
  s = x ^ c;
  cy = (a & b) | (c & x);
}

// One Zhang-Suen subiteration for one packed word, all neighbors in registers.
__device__ __forceinline__ u64 zs_regs(u64 w00, u64 w01, u64 w02,
                                       u64 w10, u64 w11, u64 w12,
                                       u64 w20, u64 w21, u64 w22, bool first) {
  const u64 P2 = w01;                          // N
  const u64 P3 = (w01 >> 1) | (w02 << 63);     // NE
  const u64 P4 = (w11 >> 1) | (w12 << 63);     // E
  const u64 P5 = (w21 >> 1) | (w22 << 63);     // SE
  const u64 P6 = w21;                          // S
  const u64 P7 = (w21 << 1) | (w20 >> 63);     // SW
  const u64 P8 = (w11 << 1) | (w10 >> 63);     // W
  const u64 P9 = (w01 << 1) | (w00 >> 63);     // NW

  u64 s1, c1, s2, c2, s3, c3, u0, u1, v1, v2;
  fa(P2, P3, P4, s1, c1);
  fa(P5, P6, P7, s2, c2);
  fa(P8, P9, 0ull, s3, c3);
  fa(s1, s2, s3, u0, u1);
  fa(c1, c2, c3, v1, v2);
  u64 b1 = u1 ^ v1, k2 = u1 & v1;
  u64 b2 = v2 ^ k2, b3 = v2 & k2;
  u64 condB = (b1 | b2 | b3) & ~(b3 | (b2 & b1 & u0));   // 2<=B<=6

  u64 t0 = ~P2 & P3, t1 = ~P3 & P4, t2 = ~P4 & P5, t3 = ~P5 & P6;
  u64 t4 = ~P6 & P7, t5 = ~P7 & P8, t6 = ~P8 & P9, t7 = ~P9 & P2;
  fa(t0, t1, t2, s1, c1);
  fa(t3, t4, t5, s2, c2);
  fa(t6, t7, 0ull, s3, c3);
  fa(s1, s2, s3, u0, u1);
  fa(c1, c2, c3, v1, v2);
  u64 a1 = u1 ^ v1, j2 = u1 & v1;
  u64 a2 = v2 ^ j2, a3 = v2 & j2;
  u64 condA = u0 & ~(a1 | a2 | a3);                      // A == 1

  u64 cc = first ? ((~(P2 & P4 & P6)) & (~(P4 & P6 & P8)))
                 : ((~(P2 & P4 & P8)) & (~(P2 & P6 & P8)));
  return w11 & ~(condB & condA & cc);
}

// Wave-frame dirty test: lane l (word idx = wb+l, wb 64-aligned) needs
// dirty3(idx-9)|dirty3(idx-1)|dirty3(idx+7) where dirty3(q) tests logical
// bits q..q+2 (logical word i at array bit 64+i). See R13 derivation.
__device__ __forceinline__ u64 dirty_wave(const u64* __restrict__ U, int mw) {
  const u64 A = U[mw - 1], B = U[mw], C = U[mw + 1], Dw = U[mw + 2];
  const u64 smA = A | (A >> 1 | B << 63) | (A >> 2 | B << 62);
  const u64 smB = B | (B >> 1 | C << 63) | (B >> 2 | C << 62);
  const u64 smC = C | (C >> 1 | Dw << 63) | (C >> 2 | Dw << 62);
  const u64 Dm9 = (smB << 9) | (smA >> 55);
  const u64 Dm1 = (smB << 1) | (smA >> 63);
  const u64 Dp7 = (smB >> 7) | (smC << 57);
  return Dm9 | Dm1 | Dp7;
}

// One pruned subiteration pass over a padded (R+2) x 8 slice in LDS.
// Clean words are fully skipped (dst holds the value from two passes ago).
// NTHR = blockDim.x; each wave's lanes cover 64 consecutive 64-aligned words.
template<int R, bool FIRST, int NTHR>
__device__ __forceinline__ void subpass(const u64* __restrict__ src, u64* __restrict__ dst,
                                        u64* rawW, const u64* rawPrev,
                                        u64* Uw, const u64* Ur,
                                        int* chgflag, int tid) {
  constexpr int NP = (R + 2) * PADW;
  int anych = 0;
  for (int base = 0; base < NP; base += NTHR) {
    const int idx = base + tid;
    int changed = 0;
    if (idx < NP) {
      const int mw = 1 + (idx >> 6);
      const u64 dmask = dirty_wave(Ur, mw);      // wave-uniform mask words
      if ((dmask >> (idx & 63)) & 1ull) {
        const u64 old = src[idx];
        u64 nw = 0;
        if (old) {
          nw = zs_regs(src[idx - PADW - 1], src[idx - PADW], src[idx - PADW + 1],
                       src[idx - 1], old, src[idx + 1],
                       src[idx + PADW - 1], src[idx + PADW], src[idx + PADW + 1], FIRST);
          changed = (nw != old);
        }
        dst[idx] = nw;
        anych |= changed;
      }
    }
    const u64 bal = __ballot(changed != 0);
    if ((tid & 63) == 0 && idx < NP) {
      const int mw = 1 + (idx >> 6);
      rawW[mw] = bal;
      Uw[mw] = bal | rawPrev[mw];
    }
  }
  if (anych) *chgflag = 1;
}

template<int MW, int NTHR>
__device__ __forceinline__ void init_masks(u64 (*raw)[MPAD2], u64 (*Um)[MPAD2], int tid) {
  for (int t = tid; t < 4 * MPAD2; t += NTHR) {
    const int arr = t / MPAD2, j = t - arr * MPAD2;
    const u64 v = ((arr & 1) && j >= 1 && j <= MW) ? ~0ull : 0ull;
    if (arr < 2) raw[arr][j] = v; else Um[arr - 2][j] = v;
  }
}

// Dense xy subpass, 256-thread block (no masks; small slices).
template<bool FIRST>
__device__ __forceinline__ void xy_dense(const u64* __restrict__ src, u64* __restrict__ dst,
                                         int* chgflag, int tid) {
  int anych = 0;
  for (int idx = tid; idx < NXY; idx += 256) {
    const u64 old = src[idx];
    u64 nw = 0;
    if (old) {
      nw = zs_regs(src[idx - PADW - 1], src[idx - PADW], src[idx - PADW + 1],
                   src[idx - 1], old, src[idx + 1],
                   src[idx + PADW - 1], src[idx + PADW], src[idx + PADW + 1], FIRST);
      anych |= (nw != old);
    }
    dst[idx] = nw;
  }
  if (anych) *chgflag = 1;
}

// Phase-A band (256 threads): exactly KA subpasses on a BROWS-row band of
// z-slice zi; exact BAND-row core written to curZ (exclusive coverage).
__device__ __forceinline__ void band_body(const u64* __restrict__ maskP,
                                          u64* __restrict__ curZ,
                                          int zi, int band, u64* Abuf, u64* Bbuf,
                                          u64 (*raw)[MPAD2], u64 (*Um)[MPAD2],
                                          int* s_chg) {
  constexpr int NP = (BROWS + 2) * PADW;   // 1040
  constexpr int MW = (NP + 63) >> 6;       // 17
  const int tid = threadIdx.x;
  const int g0 = band * BAND - HALO;       // global row of rp==1

  for (int idx = tid; idx < NP; idx += 256) {
    const int rp = idx >> 3, cp = idx & 7;
    const int g = g0 + rp - 1;
    u64 v = 0;
    if (rp >= 1 && rp <= BROWS && cp >= 1 && cp <= 6 && g >= 0 && g < H)
      v = maskP[(zi * H + g) * WPR + (cp - 1)];
    Abuf[idx] = v;
    Bbuf[idx] = 0;
  }
  init_masks<MW, 256>(raw, Um, tid);
  if (tid == 0) s_chg[0] = 0;
  __syncthreads();

  for (int t = 0; t < KA; t += 2) {
    subpass<BROWS, true, 256 >(Abuf, Bbuf, raw[0], raw[1], Um[0], Um[1], &s_chg[0], tid);
    __syncthreads();
    subpass<BROWS, false, 256>(Bbuf, Abuf, raw[1], raw[0], Um[1], Um[0], &s_chg[0], tid);
    __syncthreads();
  }

  for (int idx = tid; idx < NP; idx += 256) {
    const int rp = idx >> 3, cp = idx & 7;
    if (rp < 1 || rp > BROWS || cp < 1 || cp > 6) continue;
    const int g = g0 + rp - 1;
    if (g < band * BAND || g >= band * BAND + BAND) continue;
    curZ[(zi * H + g) * WPR + (cp - 1)] = Abuf[idx];
  }
}

// xy-slice thinning to convergence (dense, 256 threads) -> private buffer.
// MODE 1: slice=y (rows=z, cols=x) -> skelY;  MODE 2: slice=x -> skelX.
template<int MODE>
__device__ __forceinline__ void thin_xy(const u64* __restrict__ maskP,
                                        u64* __restrict__ dstBuf,
                                        int slice, u64* Abuf, u64* Bbuf,
                                        int* s_chg) {
  const int tid = threadIdx.x;

  if (MODE == 1) {
    for (int idx = tid; idx < NXY; idx += 256) {
      const int rp = idx >> 3, cp = idx & 7;
      u64 v = 0;
      if (rp >= 1 && rp <= D && cp >= 1 && cp <= 6)
        v = maskP[((rp - 1) * H + slice) * WPR + (cp - 1)];
      Abuf[idx] = v;
      Bbuf[idx] = 0;
    }
  } else {
    const int lane = tid & 63, wave = tid >> 6;      // 4 waves
    const int xw = slice >> 6, xb = slice & 63;
    for (int w = wave; w < NXY; w += 4) {
      const int rp = w >> 3, cp = w & 7;
      u64 val = 0;
      if (rp >= 1 && rp <= D && cp >= 1 && cp <= 6) {
        const int c = (cp - 1) * 64 + lane;          // c = y
        u64 bit = (maskP[((rp - 1) * H + c) * WPR + xw] >> xb) & 1ull;
        val = __ballot(bit != 0);
      }
      if (lane == 0) { Abuf[w] = val; Bbuf[w] = 0; }
    }
  }
  if (tid < 2) s_chg[tid] = 0;
  __syncthreads();

  int k = 0;
  while (true) {
    xy_dense<true >(Abuf, Bbuf, &s_chg[k], tid);
    __syncthreads();
    if (tid == 0) s_chg[k ^ 1] = 0;
    xy_dense<false>(Bbuf, Abuf, &s_chg[k], tid);
    __syncthreads();
    if (s_chg[k] == 0) break;
    k ^= 1;
  }

  for (int idx = tid; idx < NXY; idx += 256) {
    const int rp = idx >> 3, cp = idx & 7;
    if (rp < 1 || rp > D || cp < 1 || cp > 6) continue;
    const u64 w = Abuf[idx];
    if (MODE == 1) dstBuf[((rp - 1) * H + slice) * WPR + (cp - 1)] = w;
    else           dstBuf[((rp - 1) * W + slice) * WPR + (cp - 1)] = w;
  }
}

// K2 (256-thread blocks, all 960 co-resident): b<192 -> z band phase-A;
// else xy slice to convergence.
__global__ __launch_bounds__(256) void thin_bands_xy(const u64* __restrict__ maskP,
                                                     u64* __restrict__ skelY,
                                                     u64* __restrict__ skelX,
                                                     u64* __restrict__ curZ) {
  __shared__ u64 Abuf[(BROWS + 2) * PADW];   // 8.3 KB each; xy uses first 400
  __shared__ u64 Bbuf[(BROWS + 2) * PADW];
  __shared__ u64 raw[2][MPAD2];
  __shared__ u64 Um[2][MPAD2];
  __shared__ int s_chg[2];
  const int b = blockIdx.x;
  if (b < D * NBAND) {
    band_body(maskP, curZ, b >> 2, b & 3, Abuf, Bbuf, raw, Um, s_chg);
  } else {
    const int q = b - D * NBAND;
    if (q < H) thin_xy<1>(maskP, skelY, q, Abuf, Bbuf, s_chg);
    else       thin_xy<2>(maskP, skelX, q - H, Abuf, Bbuf, s_chg);
  }
}

// K3: b<48 -> z phase-B from curZ (resume at subpass KA+1; 2 forced-dense
// passes then pruned to convergence; unconditionally correct) -> skelZ.
//     b>=48 -> skelX->skelXT ballot-transpose tiles (stream order).
__global__ __launch_bounds__(1024) void thin_z_finish(const u64* __restrict__ curZ,
                                                      u64* __restrict__ skelZ,
                                                      const u64* __restrict__ skelX,
                                                      u64* __restrict__ skelXT) {
  __shared__ u64 Abuf[(H + 2) * PADW];
  __shared__ u64 Bbuf[(H + 2) * PADW];
  __shared__ u64 raw[2][MPAD2];
  __shared__ u64 Um[2][MPAD2];
  __shared__ int s_chg[2];
  const int b = blockIdx.x;
  const int tid = threadIdx.x;

  if (b < D) {
    constexpr int NP = (H + 2) * PADW;
    constexpr int MW = (NP + 63) >> 6;       // 49
    for (int idx = tid; idx < NP; idx += 1024) {
      const int rp = idx >> 3, cp = idx & 7;
      u64 v = 0;
      if (rp >= 1 && rp <= H && cp >= 1 && cp <= 6)
        v = curZ[(b * H + (rp - 1)) * WPR + (cp - 1)];
      Abuf[idx] = v;
      Bbuf[idx] = 0;
    }
    init_masks<MW, 1024>(raw, Um, tid);
    if (tid < 2) s_chg[tid] = 0;
    __syncthreads();

    int k = 0;
    while (true) {
      subpass<H, true, 1024 >(Abuf, Bbuf, raw[0], raw[1], Um[0], Um[1], &s_chg[k], tid);
      __syncthreads();
      if (tid == 0) s_chg[k ^ 1] = 0;
      subpass<H, false, 1024>(Bbuf, Abuf, raw[1], raw[0], Um[1], Um[0], &s_chg[k], tid);
      __syncthreads();
      if (s_chg[k] == 0) break;
      k ^= 1;
    }

    for (int idx = tid; idx < NP; idx += 1024) {
      const int rp = idx >> 3, cp = idx & 7;
      if (rp < 1 || rp > H || cp < 1 || cp > 6) continue;
      skelZ[(b * H + (rp - 1)) * WPR + (cp - 1)] = Abuf[idx];
    }
  } else {
    const int gw = (b - D) * 16 + (tid >> 6);   // tile id
    if (gw < NTILE) {
      const int lane = tid & 63;
      const int z = gw / 36, rem = gw - z * 36;
      const int yw = rem / 6, xw = rem - yw * 6;
      const int x = xw * 64 + lane;
      const u64 wx = skelX[(z * W + x) * WPR + yw];     // bits indexed by y
      u64 mine = 0;
      #pragma unroll 8
      for (int j = 0; j < 64; ++j) {
        u64 wj = __ballot((wx >> j) & 1ull);
        if (lane == j) mine = wj;
      }
      const int y = yw * 64 + lane;
      skelXT[(z * H + y) * WPR + xw] = mine;            // exclusive full coverage
    }
  }
}

// Pack mask bits (v==1.0f) along x into maskP. No other init needed.
__global__ void init_pack(const float* __restrict__ in, u64* __restrict__ maskP) {
  const int lane = threadIdx.x & 63;
  const int gwave = (blockIdx.x * blockDim.x + threadIdx.x) >> 6;
  const int nwaves = (gridDim.x * blockDim.x) >> 6;
  for (int widx = gwave; widx < NWVOL; widx += nwaves) {
    float v = in[(size_t)widx * 64 + lane];
    u64 w = __ballot(v == 1.0f);
    if (lane == 0) maskP[widx] = w;
  }
}

// 6-connected dilation of (skelZ | skelY | skelXT) + mask + coalesced float4
// expansion. One block = 64 words = 4096 voxels.
__global__ __launch_bounds__(256) void dilate_expand(const u64* __restrict__ maskP,
                                                     const u64* __restrict__ sZ,
                                                     const u64* __restrict__ sY,
                                                     const u64* __restrict__ sXT,
                                                     float* __restrict__ out) {
  __shared__ u64 rw[64];
  const int tid = threadIdx.x;
  const int wbase = blockIdx.x * 64;
  if (tid < 64) {
    const int wi = wbase + tid;
    const int wc = wi % WPR;
    const int row = wi / WPR;        // row = z*H + y
    const int y = row % H;
    const int z = row / H;
    const u64 S = sZ[wi] | sY[wi] | sXT[wi];
    const u64 L = (wc > 0) ? (sZ[wi - 1] | sY[wi - 1] | sXT[wi - 1]) : 0ull;
    const u64 Rw = (wc < WPR - 1) ? (sZ[wi + 1] | sY[wi + 1] | sXT[wi + 1]) : 0ull;
    u64 d = S | (S << 1) | (L >> 63) | (S >> 1) | (Rw << 63);
    if (y > 0)     d |= sZ[wi - WPR] | sY[wi - WPR] | sXT[wi - WPR];
    if (y < H - 1) d |= sZ[wi + WPR] | sY[wi + WPR] | sXT[wi + WPR];
    if (z > 0)     d |= sZ[wi - H * WPR] | sY[wi - H * WPR] | sXT[wi - H * WPR];
    if (z < D - 1) d |= sZ[wi + H * WPR] | sY[wi + H * WPR] | sXT[wi + H * WPR];
    rw[tid] = d & maskP[wi];
  }
  __syncthreads();
  float4* o4 = reinterpret_cast<float4*>(out + (size_t)wbase * 64);
  #pragma unroll
  for (int k = 0; k < 4; ++k) {
    const int f = tid + 256 * k;
    const u64 bits = rw[f >> 4] >> ((f & 15) * 4);
    float4 o;
    o.x = (float)(bits & 1ull);
    o.y = (float)((bits >> 1) & 1ull);
    o.z = (float)((bits >> 2) & 1ull);
    o.w = (float)((bits >> 3) & 1ull);
    o4[f] = o;
  }
}

extern "C" void kernel_launch(void* const* d_in, const int* in_sizes, int n_in,
                              void* d_out, int out_size, void* d_ws, size_t ws_size,
                              hipStream_t stream) {
  const float* in = (const float*)d_in[0];
  float* out = (float*)d_out;
  u64* wsw = (u64*)d_ws;                 // need 6 * 110592 * 8 B = 5.31 MB
  u64* maskP = wsw;
  u64* skelZ = wsw + NWVOL;
  u64* skelY = wsw + 2 * NWVOL;
  u64* skelX = wsw + 3 * NWVOL;
  u64* skelXT = wsw + 4 * NWVOL;
  u64* curZ = wsw + 5 * NWVOL;

  init_pack<<<1728, 256, 0, stream>>>(in, maskP);
  thin_bands_xy<<<D * NBAND + H + W, 256, 0, stream>>>(maskP, skelY, skelX, curZ);
  thin_z_finish<<<D + (NTILE + 15) / 16, 1024, 0, stream>>>(curZ, skelZ, skelX, skelXT);
  dilate_expand<<<NWVOL / 64, 256, 0, stream>>>(maskP, skelZ, skelY, skelXT, out);
}

// Round 16
// 61.825 us; speedup vs baseline: 1.4049x; 1.4049x over previous
//
#include <hip/hip_runtime.h>

typedef unsigned long long u64;

constexpr int D = 48, H = 384, W = 384;
constexpr int WPR = 6;                    // 384 bits / 64 per row (real words)
constexpr int PADW = 8;                   // padded words per row: [pad, w0..w5, pad]
constexpr int NVOX = D * H * W;           // 7,077,888
constexpr int NWVOL = D * H * WPR;        // 110,592 packed words per volume
constexpr int MPAD2 = 52;                 // padded change-mask array (u64s)
constexpr int NTILE = D * 36;             // 1728 bit-transpose tiles (64x64)

// full adder: s = a+b+c (bit-sliced), cy = carry
__device__ __forceinline__ void fa(u64 a, u64 b, u64 c, u64& s, u64& cy) {
  u64 x = a ^ b;
  s = x ^ c;
  cy = (a & b) | (c & x);
}

// One Zhang-Suen subiteration for one packed word, all neighbors in registers.
__device__ __forceinline__ u64 zs_regs(u64 w00, u64 w01, u64 w02,
                                       u64 w10, u64 w11, u64 w12,
                                       u64 w20, u64 w21, u64 w22, bool first) {
  const u64 P2 = w01;                          // N
  const u64 P3 = (w01 >> 1) | (w02 << 63);     // NE
  const u64 P4 = (w11 >> 1) | (w12 << 63);     // E
  const u64 P5 = (w21 >> 1) | (w22 << 63);     // SE
  const u64 P6 = w21;                          // S
  const u64 P7 = (w21 << 1) | (w20 >> 63);     // SW
  const u64 P8 = (w11 << 1) | (w10 >> 63);     // W
  const u64 P9 = (w01 << 1) | (w00 >> 63);     // NW

  u64 s1, c1, s2, c2, s3, c3, u0, u1, v1, v2;
  fa(P2, P3, P4, s1, c1);
  fa(P5, P6, P7, s2, c2);
  fa(P8, P9, 0ull, s3, c3);
  fa(s1, s2, s3, u0, u1);
  fa(c1, c2, c3, v1, v2);
  u64 b1 = u1 ^ v1, k2 = u1 & v1;
  u64 b2 = v2 ^ k2, b3 = v2 & k2;
  u64 condB = (b1 | b2 | b3) & ~(b3 | (b2 & b1 & u0));   // 2<=B<=6

  u64 t0 = ~P2 & P3, t1 = ~P3 & P4, t2 = ~P4 & P5, t3 = ~P5 & P6;
  u64 t4 = ~P6 & P7, t5 = ~P7 & P8, t6 = ~P8 & P9, t7 = ~P9 & P2;
  fa(t0, t1, t2, s1, c1);
  fa(t3, t4, t5, s2, c2);
  fa(t6, t7, 0ull, s3, c3);
  fa(s1, s2, s3, u0, u1);
  fa(c1, c2, c3, v1, v2);
  u64 a1 = u1 ^ v1, j2 = u1 & v1;
  u64 a2 = v2 ^ j2, a3 = v2 & j2;
  u64 condA = u0 & ~(a1 | a2 | a3);                      // A == 1

  u64 cc = first ? ((~(P2 & P4 & P6)) & (~(P4 & P6 & P8)))
                 : ((~(P2 & P4 & P8)) & (~(P2 & P6 & P8)));
  return w11 & ~(condB & condA & cc);
}

// Wave-frame dirty test: lane l (word idx = wb+l, wb 64-aligned) needs
// dirty3(idx-9)|dirty3(idx-1)|dirty3(idx+7) where dirty3(q) tests logical
// bits q..q+2 (logical word i at array bit 64+i). See R13 derivation.
__device__ __forceinline__ u64 dirty_wave(const u64* __restrict__ U, int mw) {
  const u64 A = U[mw - 1], B = U[mw], C = U[mw + 1], Dw = U[mw + 2];
  const u64 smA = A | (A >> 1 | B << 63) | (A >> 2 | B << 62);
  const u64 smB = B | (B >> 1 | C << 63) | (B >> 2 | C << 62);
  const u64 smC = C | (C >> 1 | Dw << 63) | (C >> 2 | Dw << 62);
  const u64 Dm9 = (smB << 9) | (smA >> 55);
  const u64 Dm1 = (smB << 1) | (smA >> 63);
  const u64 Dp7 = (smB >> 7) | (smC << 57);
  return Dm9 | Dm1 | Dp7;
}

// One pruned subiteration pass over a padded (R+2) x 8 slice in LDS.
// Clean words are fully skipped (dst holds the value from two passes ago).
template<int R, bool FIRST>
__device__ __forceinline__ void subpass(const u64* __restrict__ src, u64* __restrict__ dst,
                                        u64* rawW, const u64* rawPrev,
                                        u64* Uw, const u64* Ur,
                                        int* chgflag, int tid) {
  constexpr int NP = (R + 2) * PADW;
  int anych = 0;
  for (int base = 0; base < NP; base += 1024) {
    const int idx = base + tid;
    int changed = 0;
    if (idx < NP) {
      const int mw = 1 + (idx >> 6);
      const u64 dmask = dirty_wave(Ur, mw);      // wave-uniform mask words
      if ((dmask >> (idx & 63)) & 1ull) {
        const u64 old = src[idx];
        u64 nw = 0;
        if (old) {
          nw = zs_regs(src[idx - PADW - 1], src[idx - PADW], src[idx - PADW + 1],
                       src[idx - 1], old, src[idx + 1],
                       src[idx + PADW - 1], src[idx + PADW], src[idx + PADW + 1], FIRST);
          changed = (nw != old);
        }
        dst[idx] = nw;
        anych |= changed;
      }
    }
    // threads in a wave handle 64 consecutive, 64-aligned padded words
    const u64 bal = __ballot(changed != 0);
    if ((tid & 63) == 0 && idx < NP) {
      const int mw = 1 + (idx >> 6);
      rawW[mw] = bal;
      Uw[mw] = bal | rawPrev[mw];
    }
  }
  if (anych) *chgflag = 1;
}

template<int MW>
__device__ __forceinline__ void init_masks(u64 (*raw)[MPAD2], u64 (*Um)[MPAD2], int tid) {
  for (int t = tid; t < 4 * MPAD2; t += 1024) {
    const int arr = t / MPAD2, j = t - arr * MPAD2;
    const u64 v = ((arr & 1) && j >= 1 && j <= MW) ? ~0ull : 0ull;
    if (arr < 2) raw[arr][j] = v; else Um[arr - 2][j] = v;
  }
}

// Per-slice thinning to convergence, wave-frame pruned; result -> private buf.
// MODE 0: slice=z (rows=y, cols=x) R=H -> skelZ[(z*H+y)*WPR+xw]
// MODE 1: slice=y (rows=z, cols=x) R=D -> skelY[(z*H+y)*WPR+xw]
// MODE 2: slice=x (rows=z, cols=y) R=D -> skelX[(z*W+x)*WPR+yw]
template<int R, int MODE>
__device__ __forceinline__ void thin_body(const u64* __restrict__ maskP,
                                          u64* __restrict__ dstBuf,
                                          int slice, u64* Abuf, u64* Bbuf,
                                          u64 (*raw)[MPAD2], u64 (*Um)[MPAD2],
                                          int* s_chg) {
  constexpr int NP = (R + 2) * PADW;
  constexpr int MW = (NP + 63) >> 6;
  const int tid = threadIdx.x;

  // ---- load packed slice into padded LDS (zero borders), zero Bbuf ----
  if (MODE == 0 || MODE == 1) {
    for (int idx = tid; idx < NP; idx += 1024) {
      const int rp = idx >> 3, cp = idx & 7;
      u64 v = 0;
      if (rp >= 1 && rp <= R && cp >= 1 && cp <= 6) {
        if (MODE == 0) v = maskP[(slice * H + (rp - 1)) * WPR + (cp - 1)];
        else           v = maskP[((rp - 1) * H + slice) * WPR + (cp - 1)];
      }
      Abuf[idx] = v;
      Bbuf[idx] = 0;
    }
  } else {
    const int lane = tid & 63, wave = tid >> 6;       // 16 waves
    const int xw = slice >> 6, xb = slice & 63;
    for (int w = wave; w < NP; w += 16) {
      const int rp = w >> 3, cp = w & 7;
      u64 val = 0;
      if (rp >= 1 && rp <= R && cp >= 1 && cp <= 6) {
        const int c = (cp - 1) * 64 + lane;           // c = y
        u64 bit = (maskP[((rp - 1) * H + c) * WPR + xw] >> xb) & 1ull;
        val = __ballot(bit != 0);
      }
      if (lane == 0) { Abuf[w] = val; Bbuf[w] = 0; }
    }
  }

  // init masks: ones on the "previous" arrays (forces first two passes dirty)
  init_masks<MW>(raw, Um, tid);
  if (tid < 2) s_chg[tid] = 0;
  __syncthreads();

  // ---- iterate Zhang-Suen to convergence, word-pruned; 2 barriers/iter ----
  int k = 0;
  while (true) {
    subpass<R, true >(Abuf, Bbuf, raw[0], raw[1], Um[0], Um[1], &s_chg[k], tid);
    __syncthreads();
    if (tid == 0) s_chg[k ^ 1] = 0;   // prep next iter's slot
    subpass<R, false>(Bbuf, Abuf, raw[1], raw[0], Um[1], Um[0], &s_chg[k], tid);
    __syncthreads();
    if (s_chg[k] == 0) break;
    k ^= 1;
  }

  // ---- writeback: exclusive full coverage, plain stores ----
  for (int idx = tid; idx < NP; idx += 1024) {
    const int rp = idx >> 3, cp = idx & 7;
    if (rp < 1 || rp > R || cp < 1 || cp > 6) continue;
    const u64 w = Abuf[idx];
    const int r = rp - 1, wc = cp - 1;
    if (MODE == 0)      dstBuf[(slice * H + r) * WPR + wc] = w;
    else if (MODE == 1) dstBuf[(r * H + slice) * WPR + wc] = w;
    else                dstBuf[(r * W + slice) * WPR + wc] = w;
  }
}

__global__ __launch_bounds__(1024) void thin_all(const u64* __restrict__ maskP,
                                                 u64* __restrict__ skelZ,
                                                 u64* __restrict__ skelY,
                                                 u64* __restrict__ skelX) {
  __shared__ u64 Abuf[(H + 2) * PADW];  // sized for the largest mode (z-slices)
  __shared__ u64 Bbuf[(H + 2) * PADW];
  __shared__ u64 raw[2][MPAD2];
  __shared__ u64 Um[2][MPAD2];
  __shared__ int s_chg[2];
  const int b = blockIdx.x;
  if (b < D) {
    thin_body<H, 0>(maskP, skelZ, b, Abuf, Bbuf, raw, Um, s_chg);
  } else if (b < D + H) {
    thin_body<D, 1>(maskP, skelY, b - D, Abuf, Bbuf, raw, Um, s_chg);
  } else {
    thin_body<D, 2>(maskP, skelX, b - D - H, Abuf, Bbuf, raw, Um, s_chg);
  }
}

// Pack mask bits (v==1.0f) along x into maskP. No other init needed.
__global__ void init_pack(const float* __restrict__ in, u64* __restrict__ maskP) {
  const int lane = threadIdx.x & 63;
  const int gwave = (blockIdx.x * blockDim.x + threadIdx.x) >> 6;
  const int nwaves = (gridDim.x * blockDim.x) >> 6;
  for (int widx = gwave; widx < NWVOL; widx += nwaves) {
    float v = in[(size_t)widx * 64 + lane];
    u64 w = __ballot(v == 1.0f);
    if (lane == 0) maskP[widx] = w;
  }
}

// Bit-transpose skelX ([z][x][yw], packed y) -> skelXT ([z][y][xw], packed x).
// One wave per 64x64 bit tile; every word written (exclusive, no init needed).
__global__ void transpose_x(const u64* __restrict__ skelX,
                            u64* __restrict__ skelXT) {
  const int gw = (blockIdx.x * blockDim.x + threadIdx.x) >> 6;   // tile id
  const int lane = threadIdx.x & 63;
  const int z = gw / 36, rem = gw - z * 36;
  const int yw = rem / 6, xw = rem - yw * 6;
  const int x = xw * 64 + lane;
  const u64 wx = skelX[(z * W + x) * WPR + yw];   // bits indexed by y
  u64 mine = 0;
  #pragma unroll 8
  for (int j = 0; j < 64; ++j) {
    u64 wj = __ballot((wx >> j) & 1ull);          // bit l = pixel(y=yw*64+j, x=xw*64+l)
    if (lane == j) mine = wj;
  }
  const int y = yw * 64 + lane;
  skelXT[(z * H + y) * WPR + xw] = mine;
}

// 6-connected dilation of (skelZ | skelY | skelXT) + mask + coalesced float4
// expansion. One block = 64 words = 4096 voxels.
__global__ __launch_bounds__(256) void dilate_expand(const u64* __restrict__ maskP,
                                                     const u64* __restrict__ sZ,
                                                     const u64* __restrict__ sY,
                                                     const u64* __restrict__ sXT,
                                                     float* __restrict__ out) {
  __shared__ u64 rw[64];
  const int tid = threadIdx.x;
  const int wbase = blockIdx.x * 64;
  if (tid < 64) {
    const int wi = wbase + tid;
    const int wc = wi % WPR;
    const int row = wi / WPR;        // row = z*H + y
    const int y = row % H;
    const int z = row / H;
    const u64 S = sZ[wi] | sY[wi] | sXT[wi];
    const u64 L = (wc > 0) ? (sZ[wi - 1] | sY[wi - 1] | sXT[wi - 1]) : 0ull;
    const u64 Rw = (wc < WPR - 1) ? (sZ[wi + 1] | sY[wi + 1] | sXT[wi + 1]) : 0ull;
    u64 d = S | (S << 1) | (L >> 63) | (S >> 1) | (Rw << 63);
    if (y > 0)     d |= sZ[wi - WPR] | sY[wi - WPR] | sXT[wi - WPR];
    if (y < H - 1) d |= sZ[wi + WPR] | sY[wi + WPR] | sXT[wi + WPR];
    if (z > 0)     d |= sZ[wi - H * WPR] | sY[wi - H * WPR] | sXT[wi - H * WPR];
    if (z < D - 1) d |= sZ[wi + H * WPR] | sY[wi + H * WPR] | sXT[wi + H * WPR];
    rw[tid] = d & maskP[wi];
  }
  __syncthreads();
  float4* o4 = reinterpret_cast<float4*>(out + (size_t)wbase * 64);
  #pragma unroll
  for (int k = 0; k < 4; ++k) {
    const int f = tid + 256 * k;             // float4 index within the block's 1024
    const u64 bits = rw[f >> 4] >> ((f & 15) * 4);
    float4 o;
    o.x = (float)(bits & 1ull);
    o.y = (float)((bits >> 1) & 1ull);
    o.z = (float)((bits >> 2) & 1ull);
    o.w = (float)((bits >> 3) & 1ull);
    o4[f] = o;
  }
}

extern "C" void kernel_launch(void* const* d_in, const int* in_sizes, int n_in,
                              void* d_out, int out_size, void* d_ws, size_t ws_size,
                              hipStream_t stream) {
  const float* in = (const float*)d_in[0];
  float* out = (float*)d_out;
  u64* wsw = (u64*)d_ws;                 // need 5 * 110592 * 8 B = 4.42 MB
  u64* maskP = wsw;
  u64* skelZ = wsw + NWVOL;
  u64* skelY = wsw + 2 * NWVOL;
  u64* skelX = wsw + 3 * NWVOL;
  u64* skelXT = wsw + 4 * NWVOL;

  init_pack<<<1728, 256, 0, stream>>>(in, maskP);
  thin_all<<<D + H + W, 1024, 0, stream>>>(maskP, skelZ, skelY, skelX);
  transpose_x<<<(NTILE * 64) / 256, 256, 0, stream>>>(skelX, skelXT);
  dilate_expand<<<NWVOL / 64, 256, 0, stream>>>(maskP, skelZ, skelY, skelXT, out);
}